// Round 11
// baseline (43.350 us; speedup 1.0000x reference)
//
#include <hip/hip_runtime.h>
#include <hip/hip_bf16.h>

#define B_   16
#define L_   256
#define D_   512
#define C_   8
#define P_   12
#define LOUT 244
#define O_   512
#define GM   3904   // 16*244 rows per channel
#define BM   128
#define BN   128
#define BK   32
#define NMT  31     // ceil(3904/128)
#define NNT  4
#define NSTEP 16    // D_/BK

typedef __attribute__((ext_vector_type(8))) short bf16x8;
typedef __attribute__((ext_vector_type(4))) float f32x4;

__device__ __forceinline__ unsigned short f2bf(float f) {
    unsigned int u = __float_as_uint(f);
    unsigned int r = (u + 0x7FFFu + ((u >> 16) & 1u)) >> 16;
    return (unsigned short)r;
}

__device__ __forceinline__ void async_copy16(const void* g, void* l) {
    __builtin_amdgcn_global_load_lds(
        (const __attribute__((address_space(1))) unsigned int*)g,
        (__attribute__((address_space(3))) unsigned int*)l, 16, 0, 0);
}

// ---------------------------------------------------------------------------
// prep (round-2 verbatim, verified passing twice):
//   blocks [0,976):  tmp[c][b][l][d] = sum_p Wt[c,p]*inp[b,l+p,d] (bf16);
//                    one inp read serves all 8 channels.
//   blocks [976,3024): Ws f32 -> bf16.
// ---------------------------------------------------------------------------
__global__ __launch_bounds__(256) void prep(const float* __restrict__ inp,
                                            const float* __restrict__ Ws,
                                            const float* __restrict__ Wt,
                                            unsigned short* __restrict__ tmp,
                                            unsigned short* __restrict__ wsb) {
    int bid = blockIdx.x;
    int tid = threadIdx.x;

    if (bid >= 976) {                       // ---- Ws convert path ----
        int g = (bid - 976) * 256 + tid;    // 524288 float4s
        float4 v = ((const float4*)Ws)[g];
        ushort4 o;
        o.x = f2bf(v.x); o.y = f2bf(v.y); o.z = f2bf(v.z); o.w = f2bf(v.w);
        ((ushort4*)wsb)[g] = o;
        return;
    }

    // ---- FIR path ----
    __shared__ float wt_s[C_][P_];
    if (tid < C_ * P_) wt_s[tid / P_][tid % P_] = Wt[tid];
    __syncthreads();

    int b = bid / 61, lg = bid % 61;
    int l0 = lg * 4;
    int d0 = tid * 2;

    float2 rows[15];
    const float* ibase = inp + ((size_t)b * L_ + l0) * D_ + d0;
#pragma unroll
    for (int j = 0; j < 15; ++j)
        rows[j] = *(const float2*)(ibase + (size_t)j * D_);

#pragma unroll
    for (int c = 0; c < C_; ++c) {
        float w[P_];
#pragma unroll
        for (int p = 0; p < P_; ++p) w[p] = wt_s[c][p];
        unsigned short* ob = tmp + (((size_t)(c * B_ + b)) * LOUT + l0) * D_ + d0;
#pragma unroll
        for (int j = 0; j < 4; ++j) {
            float vx = 0.f, vy = 0.f;
#pragma unroll
            for (int p = 0; p < P_; ++p) {
                vx += w[p] * rows[j + p].x;
                vy += w[p] * rows[j + p].y;
            }
            ushort2 ov; ov.x = f2bf(vx); ov.y = f2bf(vy);
            *(ushort2*)(ob + (size_t)j * D_) = ov;
        }
    }
}

// ---------------------------------------------------------------------------
// gemm: per (c,mt,nt): out[r,o] = tmp_c[r,:] . Ws_c[o,:] + S*bs + bt
//   128x128 tile, 256 thr = 4 waves (2x2), wave tile 64x64, acc[4][4].
//   BK=32 -> LDS dbuf 32 KB -> 4 blocks/CU; 992 blocks = one dispatch round.
//   PROVABLE pipeline (round-10 post-mortem):
//     - prologue drains vmcnt(0): both stages certified; loop vmcnt(4)
//       certifies t+1 by GROUP order only (regions separated by
//       memory-clobbering asm - loads/stores cannot cross).
//     - lgkmcnt(0)+sched_barrier(0) BEFORE the read-done barrier: ds_reads
//       complete before any wave's STAGE DMA can overwrite (rule 18 dual).
//   Staging: global_load_lds x16, linear dest + source swizzle cc^(row&3),
//   reads apply same XOR.
//   bid = ((mt*4+nt))*8 + c: channel per XCD; nt-siblings time-adjacent.
// ---------------------------------------------------------------------------
__global__ __launch_bounds__(256, 4) void gemm_k(const unsigned short* __restrict__ tmp,
                                                 const unsigned short* __restrict__ wsb,
                                                 const float* __restrict__ bs,
                                                 const float* __restrict__ Wt,
                                                 const float* __restrict__ bt,
                                                 float* __restrict__ out) {
    __shared__ unsigned short As0[BM * BK], As1[BM * BK];   // 8 KB each
    __shared__ unsigned short Bs0[BN * BK], Bs1[BN * BK];   // 8 KB each

    int bid = blockIdx.x;
    int c  = bid & 7;
    int t2 = bid >> 3;                 // 0..123
    int nt = t2 & 3;
    int mt = t2 >> 2;                  // 0..30
    int row0 = mt * BM;
    int o0   = nt * BN;
    int tid = threadIdx.x, lane = tid & 63, wid = tid >> 6;
    int wm = wid >> 1, wn = wid & 1;   // 2 x 2 wave grid; wave tile 64x64

    const unsigned short* Ab = tmp + (size_t)c * GM * D_;
    const unsigned short* Bb = wsb + ((size_t)c * O_ + o0) * D_;

    f32x4 acc[4][4];
#pragma unroll
    for (int m = 0; m < 4; ++m)
#pragma unroll
        for (int n = 0; n < 4; ++n)
            acc[m][n] = (f32x4){0.f, 0.f, 0.f, 0.f};

    unsigned short *Ac = As0, *Bc = Bs0, *An = As1, *Bn = Bs1;

    // per stage: A 512 chunks + B 512 chunks; 2+2 insts per thread
#define STAGE(dstA, dstB, kb)                                                 \
    _Pragma("unroll")                                                         \
    for (int h = 0; h < 2; ++h) {                                             \
        int q = h * 256 + tid;                                                \
        int row = q >> 2, cc = q & 3;                                         \
        int sc = cc ^ (row & 3);                                              \
        int ar = row0 + row; if (ar > GM - 1) ar = GM - 1;                    \
        async_copy16(Ab + (size_t)ar * D_ + (kb) + sc * 8, (dstA) + q * 8);   \
        async_copy16(Bb + (size_t)row * D_ + (kb) + sc * 8, (dstB) + q * 8);  \
    }

    // one K=32 slice: 4x4 MFMA per wave
#define MFMA_STEP(Asrc, Bsrc)                                                 \
    {                                                                         \
        bf16x8 af[4], bq[4];                                                  \
        _Pragma("unroll")                                                     \
        for (int m = 0; m < 4; ++m) {                                         \
            int r = wm * 64 + m * 16 + (lane & 15);                           \
            af[m] = *(const bf16x8*)&(Asrc)[r * BK +                          \
                    (((lane >> 4) ^ (r & 3)) << 3)];                          \
        }                                                                     \
        _Pragma("unroll")                                                     \
        for (int n = 0; n < 4; ++n) {                                         \
            int o = wn * 64 + n * 16 + (lane & 15);                           \
            bq[n] = *(const bf16x8*)&(Bsrc)[o * BK +                          \
                    (((lane >> 4) ^ (o & 3)) << 3)];                          \
        }                                                                     \
        _Pragma("unroll")                                                     \
        for (int m = 0; m < 4; ++m)                                           \
            _Pragma("unroll")                                                 \
            for (int n = 0; n < 4; ++n)                                       \
                acc[m][n] = __builtin_amdgcn_mfma_f32_16x16x32_bf16(          \
                    af[m], bq[n], acc[m][n], 0, 0, 0);                        \
    }

    // ---- prologue: stage 0 and 1, drain BOTH (provable certification) ----
    STAGE(Ac, Bc, 0)
    STAGE(An, Bn, BK)
    asm volatile("s_waitcnt vmcnt(0)" ::: "memory");
    __builtin_amdgcn_sched_barrier(0);
    asm volatile("s_barrier" ::: "memory");

    // ---- K-loop: 16 steps, counted vmcnt, provable ordering ----
#pragma unroll
    for (int t = 0; t < NSTEP; ++t) {
        MFMA_STEP(Ac, Bc)
        if (t == NSTEP - 1) break;
        // ds_reads of step t MUST complete before any wave's DMA overwrite:
        asm volatile("s_waitcnt lgkmcnt(0)" ::: "memory");
        __builtin_amdgcn_sched_barrier(0);
        asm volatile("s_barrier" ::: "memory");          // read-done barrier
        if (t + 2 < NSTEP) STAGE(Ac, Bc, (t + 2) * BK)   // refill buffer just read
        if (t < NSTEP - 2)
            asm volatile("s_waitcnt vmcnt(4)" ::: "memory");  // certify stage t+1
        else
            asm volatile("s_waitcnt vmcnt(0)" ::: "memory");  // tail
        __builtin_amdgcn_sched_barrier(0);
        asm volatile("s_barrier" ::: "memory");          // buffer-ready barrier
        unsigned short* tp;
        tp = Ac; Ac = An; An = tp;
        tp = Bc; Bc = Bn; Bn = tp;
    }

    // ---- bias + store ----
    float S = 0.f;
#pragma unroll
    for (int p = 0; p < P_; ++p) S += Wt[c * P_ + p];
    float btc = bt[c];

#pragma unroll
    for (int m = 0; m < 4; ++m) {
        int rb = row0 + wm * 64 + m * 16 + ((lane >> 4) << 2);
#pragma unroll
        for (int n = 0; n < 4; ++n) {
            int col = o0 + wn * 64 + n * 16 + (lane & 15);
            float add = bs[c * O_ + col] * S + btc;
#pragma unroll
            for (int i = 0; i < 4; ++i) {
                int r = rb + i;
                if (r < GM)
                    out[((size_t)r * C_ + c) * O_ + col] = acc[m][n][i] + add;
            }
        }
    }
#undef STAGE
#undef MFMA_STEP
}

// ---------------------------------------------------------------------------
// Fallback (ws too small): slow but correct, no workspace.
// ---------------------------------------------------------------------------
__global__ __launch_bounds__(256) void naive_k(const float* __restrict__ inp,
                                               const float* __restrict__ Ws,
                                               const float* __restrict__ bs,
                                               const float* __restrict__ Wt,
                                               const float* __restrict__ bt,
                                               float* __restrict__ out) {
    __shared__ float tmp[D_];
    int bid = blockIdx.x;
    int c = bid & 7; int r = bid >> 3;
    int l = r % LOUT; int b = r / LOUT;
    int tid = threadIdx.x;

    for (int d = tid; d < D_; d += 256) {
        float s = 0.f;
        for (int p = 0; p < P_; ++p)
            s += Wt[c * P_ + p] * inp[((size_t)b * L_ + l + p) * D_ + d];
        tmp[d] = s;
    }
    __syncthreads();
    float S = 0.f;
    for (int p = 0; p < P_; ++p) S += Wt[c * P_ + p];
    for (int o = tid; o < O_; o += 256) {
        const float* wrow = Ws + ((size_t)c * O_ + o) * D_;
        float s = 0.f;
        for (int d = 0; d < D_; ++d) s += wrow[d] * tmp[d];
        out[(((size_t)b * LOUT + l) * C_ + c) * O_ + o] =
            s + bs[c * O_ + o] * S + bt[c];
    }
}

extern "C" void kernel_launch(void* const* d_in, const int* in_sizes, int n_in,
                              void* d_out, int out_size, void* d_ws, size_t ws_size,
                              hipStream_t stream) {
    const float* inp = (const float*)d_in[0];
    const float* Ws  = (const float*)d_in[1];
    const float* bs  = (const float*)d_in[2];
    const float* Wt  = (const float*)d_in[3];
    const float* bt  = (const float*)d_in[4];
    float* out = (float*)d_out;

    const size_t TMPB = (size_t)C_ * GM * D_ * 2;   // 31,981,568
    const size_t WSBB = (size_t)C_ * O_ * D_ * 2;   //  4,194,304

    if (ws_size >= TMPB + WSBB) {
        unsigned short* tmpb = (unsigned short*)d_ws;
        unsigned short* wsb  = (unsigned short*)((char*)d_ws + TMPB);
        prep<<<3024, 256, 0, stream>>>(inp, Ws, Wt, tmpb, wsb);
        gemm_k<<<NMT * NNT * C_, 256, 0, stream>>>(tmpb, wsb, bs, Wt, bt, out);
    } else {
        naive_k<<<B_ * LOUT * C_, 256, 0, stream>>>(inp, Ws, bs, Wt, bt, out);
    }
}

// Round 12
// 42.733 us; speedup vs baseline: 1.0144x; 1.0144x over previous
//
#include <hip/hip_runtime.h>
#include <hip/hip_bf16.h>

#define B_   16
#define L_   256
#define D_   512
#define C_   8
#define P_   12
#define LOUT 244
#define O_   512
#define GM   3904   // 16*244 rows per channel
#define BM   128
#define BN   256
#define BK   32
#define NMT  31     // ceil(3904/128)
#define NNT  2
#define NSTEP 16    // D_/BK

typedef __attribute__((ext_vector_type(8))) short bf16x8;
typedef __attribute__((ext_vector_type(4))) float f32x4;

__device__ __forceinline__ unsigned short f2bf(float f) {
    unsigned int u = __float_as_uint(f);
    unsigned int r = (u + 0x7FFFu + ((u >> 16) & 1u)) >> 16;
    return (unsigned short)r;
}

__device__ __forceinline__ void async_copy16(const void* g, void* l) {
    __builtin_amdgcn_global_load_lds(
        (const __attribute__((address_space(1))) unsigned int*)g,
        (__attribute__((address_space(3))) unsigned int*)l, 16, 0, 0);
}

// ---------------------------------------------------------------------------
// prep (round-2 verbatim, verified passing 3x):
//   blocks [0,976):  tmp[c][b][l][d] = sum_p Wt[c,p]*inp[b,l+p,d] (bf16);
//                    one inp read serves all 8 channels.
//   blocks [976,3024): Ws f32 -> bf16.
// ---------------------------------------------------------------------------
__global__ __launch_bounds__(256) void prep(const float* __restrict__ inp,
                                            const float* __restrict__ Ws,
                                            const float* __restrict__ Wt,
                                            unsigned short* __restrict__ tmp,
                                            unsigned short* __restrict__ wsb) {
    int bid = blockIdx.x;
    int tid = threadIdx.x;

    if (bid >= 976) {                       // ---- Ws convert path ----
        int g = (bid - 976) * 256 + tid;    // 524288 float4s
        float4 v = ((const float4*)Ws)[g];
        ushort4 o;
        o.x = f2bf(v.x); o.y = f2bf(v.y); o.z = f2bf(v.z); o.w = f2bf(v.w);
        ((ushort4*)wsb)[g] = o;
        return;
    }

    // ---- FIR path ----
    __shared__ float wt_s[C_][P_];
    if (tid < C_ * P_) wt_s[tid / P_][tid % P_] = Wt[tid];
    __syncthreads();

    int b = bid / 61, lg = bid % 61;
    int l0 = lg * 4;
    int d0 = tid * 2;

    float2 rows[15];
    const float* ibase = inp + ((size_t)b * L_ + l0) * D_ + d0;
#pragma unroll
    for (int j = 0; j < 15; ++j)
        rows[j] = *(const float2*)(ibase + (size_t)j * D_);

#pragma unroll
    for (int c = 0; c < C_; ++c) {
        float w[P_];
#pragma unroll
        for (int p = 0; p < P_; ++p) w[p] = wt_s[c][p];
        unsigned short* ob = tmp + (((size_t)(c * B_ + b)) * LOUT + l0) * D_ + d0;
#pragma unroll
        for (int j = 0; j < 4; ++j) {
            float vx = 0.f, vy = 0.f;
#pragma unroll
            for (int p = 0; p < P_; ++p) {
                vx += w[p] * rows[j + p].x;
                vy += w[p] * rows[j + p].y;
            }
            ushort2 ov; ov.x = f2bf(vx); ov.y = f2bf(vy);
            *(ushort2*)(ob + (size_t)j * D_) = ov;
        }
    }
}

// ---------------------------------------------------------------------------
// gemm: per (c,mt,nt): out[r,o] = tmp_c[r,:] . Ws_c[o,:] + S*bs + bt
//   128x256 tile (NNT=2 halves A restaging: 190 MB total DMA), BK=32,
//   512 thr = 8 waves (2m x 4n), wave tile 64x64, acc[4][4].
//   TRIPLE buffer (72 KB LDS -> 2 blocks/CU), ONE barrier per K-step:
//     MFMA(t) -> lgkmcnt(0) -> STAGE(t+2 -> buf(t+2)%3) -> vmcnt(3)
//     (certify t+1; 0 at tail) -> s_barrier.
//   Safety: buf(t+2)%3's readers (step t-1) all lgkm-drained before the
//   barrier separating t-1 from t; vmcnt certify-before-barrier makes
//   stage t+1 visible to all waves at entry of step t+1 (round-11 scheme).
//   Staging: global_load_lds x16, linear dest + source swizzle cc^(row&3),
//   reads apply same XOR (residual 4-way on A, acceptable).
//   bid: c = bid&7 (channel per XCD), nt-siblings time-adjacent.
// ---------------------------------------------------------------------------
__global__ __launch_bounds__(512, 4) void gemm_k(const unsigned short* __restrict__ tmp,
                                                 const unsigned short* __restrict__ wsb,
                                                 const float* __restrict__ bs,
                                                 const float* __restrict__ Wt,
                                                 const float* __restrict__ bt,
                                                 float* __restrict__ out) {
    __shared__ unsigned short As[3][BM * BK];   // 3 x 8 KB
    __shared__ unsigned short Bs[3][BN * BK];   // 3 x 16 KB

    int bid = blockIdx.x;
    int c  = bid & 7;
    int t2 = bid >> 3;                 // 0..61
    int nt = t2 & 1;
    int mt = t2 >> 1;                  // 0..30
    int row0 = mt * BM;
    int o0   = nt * BN;
    int tid = threadIdx.x, lane = tid & 63, wid = tid >> 6;
    int wm = wid >> 2, wn = wid & 3;   // 2 x 4 wave grid; wave tile 64x64

    const unsigned short* Ab = tmp + (size_t)c * GM * D_;
    const unsigned short* Bb = wsb + ((size_t)c * O_ + o0) * D_;

    f32x4 acc[4][4];
#pragma unroll
    for (int m = 0; m < 4; ++m)
#pragma unroll
        for (int n = 0; n < 4; ++n)
            acc[m][n] = (f32x4){0.f, 0.f, 0.f, 0.f};

    // per stage: A 512 chunks (1/thread) + B 1024 chunks (2/thread) = 3 insts
#define STAGE(bi, kb)                                                         \
    {                                                                         \
        int qa = tid;                                                         \
        int rowa = qa >> 2, cca = qa & 3;                                     \
        int sca = cca ^ (rowa & 3);                                           \
        int ar = row0 + rowa; if (ar > GM - 1) ar = GM - 1;                   \
        async_copy16(Ab + (size_t)ar * D_ + (kb) + sca * 8,                   \
                     (unsigned short*)As[bi] + qa * 8);                       \
        _Pragma("unroll")                                                     \
        for (int h = 0; h < 2; ++h) {                                         \
            int q = h * 512 + tid;                                            \
            int row = q >> 2, cc = q & 3;                                     \
            int sc = cc ^ (row & 3);                                          \
            async_copy16(Bb + (size_t)row * D_ + (kb) + sc * 8,               \
                         (unsigned short*)Bs[bi] + q * 8);                    \
        }                                                                     \
    }

    // one K=32 slice: 4x4 MFMA per wave
#define MFMA_STEP(bi)                                                         \
    {                                                                         \
        bf16x8 af[4], bq[4];                                                  \
        _Pragma("unroll")                                                     \
        for (int m = 0; m < 4; ++m) {                                         \
            int r = wm * 64 + m * 16 + (lane & 15);                           \
            af[m] = *(const bf16x8*)&As[bi][r * BK +                          \
                    (((lane >> 4) ^ (r & 3)) << 3)];                          \
        }                                                                     \
        _Pragma("unroll")                                                     \
        for (int n = 0; n < 4; ++n) {                                         \
            int o = wn * 64 + n * 16 + (lane & 15);                           \
            bq[n] = *(const bf16x8*)&Bs[bi][o * BK +                          \
                    (((lane >> 4) ^ (o & 3)) << 3)];                          \
        }                                                                     \
        _Pragma("unroll")                                                     \
        for (int m = 0; m < 4; ++m)                                           \
            _Pragma("unroll")                                                 \
            for (int n = 0; n < 4; ++n)                                       \
                acc[m][n] = __builtin_amdgcn_mfma_f32_16x16x32_bf16(          \
                    af[m], bq[n], acc[m][n], 0, 0, 0);                        \
    }

    // ---- prologue: stage 0,1; drain both (provable); barrier ----
    STAGE(0, 0)
    STAGE(1, BK)
    asm volatile("s_waitcnt vmcnt(0)" ::: "memory");
    __builtin_amdgcn_sched_barrier(0);
    asm volatile("s_barrier" ::: "memory");

    // ---- K-loop: 16 steps, 3-buffer, ONE barrier per step ----
#pragma unroll
    for (int t = 0; t < NSTEP; ++t) {
        MFMA_STEP(t % 3)
        if (t == NSTEP - 1) break;
        // our ds_reads of step t must land before anyone's DMA overwrite:
        asm volatile("s_waitcnt lgkmcnt(0)" ::: "memory");
        __builtin_amdgcn_sched_barrier(0);
        if (t + 2 < NSTEP) STAGE((t + 2) % 3, (t + 2) * BK)
        if (t < NSTEP - 2)
            asm volatile("s_waitcnt vmcnt(3)" ::: "memory");  // certify t+1
        else
            asm volatile("s_waitcnt vmcnt(0)" ::: "memory");  // tail
        __builtin_amdgcn_sched_barrier(0);
        asm volatile("s_barrier" ::: "memory");   // step separator
    }

    // ---- bias + store ----
    float S = 0.f;
#pragma unroll
    for (int p = 0; p < P_; ++p) S += Wt[c * P_ + p];
    float btc = bt[c];

#pragma unroll
    for (int m = 0; m < 4; ++m) {
        int rb = row0 + wm * 64 + m * 16 + ((lane >> 4) << 2);
#pragma unroll
        for (int n = 0; n < 4; ++n) {
            int col = o0 + wn * 64 + n * 16 + (lane & 15);
            float add = bs[c * O_ + col] * S + btc;
#pragma unroll
            for (int i = 0; i < 4; ++i) {
                int r = rb + i;
                if (r < GM)
                    out[((size_t)r * C_ + c) * O_ + col] = acc[m][n][i] + add;
            }
        }
    }
#undef STAGE
#undef MFMA_STEP
}

// ---------------------------------------------------------------------------
// Fallback (ws too small): slow but correct, no workspace.
// ---------------------------------------------------------------------------
__global__ __launch_bounds__(256) void naive_k(const float* __restrict__ inp,
                                               const float* __restrict__ Ws,
                                               const float* __restrict__ bs,
                                               const float* __restrict__ Wt,
                                               const float* __restrict__ bt,
                                               float* __restrict__ out) {
    __shared__ float tmp[D_];
    int bid = blockIdx.x;
    int c = bid & 7; int r = bid >> 3;
    int l = r % LOUT; int b = r / LOUT;
    int tid = threadIdx.x;

    for (int d = tid; d < D_; d += 256) {
        float s = 0.f;
        for (int p = 0; p < P_; ++p)
            s += Wt[c * P_ + p] * inp[((size_t)b * L_ + l + p) * D_ + d];
        tmp[d] = s;
    }
    __syncthreads();
    float S = 0.f;
    for (int p = 0; p < P_; ++p) S += Wt[c * P_ + p];
    for (int o = tid; o < O_; o += 256) {
        const float* wrow = Ws + ((size_t)c * O_ + o) * D_;
        float s = 0.f;
        for (int d = 0; d < D_; ++d) s += wrow[d] * tmp[d];
        out[(((size_t)b * LOUT + l) * C_ + c) * O_ + o] =
            s + bs[c * O_ + o] * S + bt[c];
    }
}

extern "C" void kernel_launch(void* const* d_in, const int* in_sizes, int n_in,
                              void* d_out, int out_size, void* d_ws, size_t ws_size,
                              hipStream_t stream) {
    const float* inp = (const float*)d_in[0];
    const float* Ws  = (const float*)d_in[1];
    const float* bs  = (const float*)d_in[2];
    const float* Wt  = (const float*)d_in[3];
    const float* bt  = (const float*)d_in[4];
    float* out = (float*)d_out;

    const size_t TMPB = (size_t)C_ * GM * D_ * 2;   // 31,981,568
    const size_t WSBB = (size_t)C_ * O_ * D_ * 2;   //  4,194,304

    if (ws_size >= TMPB + WSBB) {
        unsigned short* tmpb = (unsigned short*)d_ws;
        unsigned short* wsb  = (unsigned short*)((char*)d_ws + TMPB);
        prep<<<3024, 256, 0, stream>>>(inp, Ws, Wt, tmpb, wsb);
        gemm_k<<<NMT * NNT * C_, 512, 0, stream>>>(tmpb, wsb, bs, Wt, bt, out);
    } else {
        naive_k<<<B_ * LOUT * C_, 256, 0, stream>>>(inp, Ws, bs, Wt, bt, out);
    }
}